// Round 8
// baseline (234.031 us; speedup 1.0000x reference)
//
#include <hip/hip_runtime.h>

#define ORDER 1024
#define NCOEF 1025
#define BATCH 8192

typedef float v2 __attribute__((ext_vector_type(2)));
typedef float v8sf __attribute__((ext_vector_type(8)));

// lane i reads lane i-1; lane 0 reads 0 (bound_ctrl). Single VALU instr.
__device__ __forceinline__ float wave_shr1(float v) {
    int r = __builtin_amdgcn_update_dpp(0, __float_as_int(v),
                                        0x138 /*wave_shr:1*/, 0xf, 0xf, true);
    return __int_as_float(r);
}

// 8 roots -> SGPRs on the scalar pipe (no VALU, no vmcnt).
__device__ __forceinline__ v8sf s_load8(const float* p) {
    v8sf r;
    asm volatile("s_load_dwordx8 %0, %1, 0x0" : "=s"(r) : "s"(p));
    return r;
}
__device__ __forceinline__ void s_wait8(v8sf& r) {
    asm volatile("s_waitcnt lgkmcnt(0)" : "+s"(r));
}

// Lane-local coefficient bank, stride-9 pairing on the 17-coeff cycle:
//   p[m] = (c_m, c_{m+9})  for m=0..7 ; x = (dpp scratch, c_8)
// Shift-by-1 source of p[m] is p[m-1] (aligned -> v_pk_fma_f32).
// IN-PLACE update: descending m reads old p[m-1] before overwrite.
struct Bank { v2 p[8]; v2 x; };

__device__ __forceinline__ void init_bank(Bank& A, bool lane0) {
#pragma unroll
    for (int m = 0; m < 8; ++m) { A.p[m].x = 0.0f; A.p[m].y = 0.0f; }
    A.x.x = 0.0f; A.x.y = 0.0f;
    if (lane0) A.p[0].x = 1.0f;   // c_0 = 1: empty product
}

__device__ __forceinline__ void step(Bank& A, float nx) {
    v2 nxp; nxp.x = nx; nxp.y = nx;
    const float t = wave_shr1(A.p[7].y);                     // prev lane old c_16
    const float c8new = __builtin_fmaf(nx, A.p[7].x, A.x.y); // old c_7, old c_8
    v2 xold; xold.x = t; xold.y = A.x.y;                     // (c_{-1}, c_8) old
#pragma unroll
    for (int m = 7; m >= 1; --m)
        A.p[m] = __builtin_elementwise_fma(nxp, A.p[m - 1], A.p[m]);
    A.p[0] = __builtin_elementwise_fma(nxp, xold, A.p[0]);
    A.x.y = c8new;
}

__device__ __forceinline__ void store_bank(const Bank& A, float* __restrict__ orow,
                                           int lane) {
#pragma unroll
    for (int j = 0; j < 8; ++j) {
        const int k = lane * 17 + j;
        if (k < NCOEF) orow[k] = A.p[j].x;
    }
    {
        const int k = lane * 17 + 8;
        if (k < NCOEF) orow[k] = A.x.y;
    }
#pragma unroll
    for (int j = 9; j < 17; ++j) {
        const int k = lane * 17 + j;
        if (k < NCOEF) orow[k] = A.p[j - 9].y;
    }
}

// TWO rows per wave, steps interleaved: two independent dependency chains
// double per-wave ILP so latency bubbles in one chain are filled by the
// other (breaks the lockstep phase-alignment of identical waves).
__global__ __launch_bounds__(256) void r2p_kernel(const float* __restrict__ x,
                                                  float* __restrict__ out) {
    const int wave = threadIdx.x >> 6;
    const int lane = threadIdx.x & 63;
    int wid = (int)blockIdx.x * 4 + wave;          // 0..4095
    wid = __builtin_amdgcn_readfirstlane(wid);
    const int row0 = wid * 2;
    const int row1 = row0 + 1;

    const float* __restrict__ xr0 = x + (size_t)row0 * ORDER;
    const float* __restrict__ xr1 = x + (size_t)row1 * ORDER;

    Bank A0, A1;
    const bool lane0 = (lane == 0);
    init_bank(A0, lane0);
    init_bank(A1, lane0);

    v8sf c0 = s_load8(xr0);
    v8sf c1 = s_load8(xr1);
    s_wait8(c0); s_wait8(c1);
    for (int i = 0; i < ORDER; i += 8) {
        const int nextoff = (i + 8 < ORDER) ? (i + 8) : i;   // uniform, SALU
        v8sf n0 = s_load8(xr0 + nextoff);
        v8sf n1 = s_load8(xr1 + nextoff);

        step(A0, -c0.s0); step(A1, -c1.s0);
        step(A0, -c0.s1); step(A1, -c1.s1);
        step(A0, -c0.s2); step(A1, -c1.s2);
        step(A0, -c0.s3); step(A1, -c1.s3);
        step(A0, -c0.s4); step(A1, -c1.s4);
        step(A0, -c0.s5); step(A1, -c1.s5);
        step(A0, -c0.s6); step(A1, -c1.s6);
        step(A0, -c0.s7); step(A1, -c1.s7);

        s_wait8(n0); s_wait8(n1);
        c0 = n0; c1 = n1;
    }

    store_bank(A0, out + (size_t)row0 * NCOEF, lane);
    store_bank(A1, out + (size_t)row1 * NCOEF, lane);
}

extern "C" void kernel_launch(void* const* d_in, const int* in_sizes, int n_in,
                              void* d_out, int out_size, void* d_ws, size_t ws_size,
                              hipStream_t stream) {
    const float* x = (const float*)d_in[0];
    float* out = (float*)d_out;
    dim3 grid(BATCH / 8);  // 4 waves/block x 2 rows/wave
    dim3 block(256);
    hipLaunchKernelGGL(r2p_kernel, grid, block, 0, stream, x, out);
}

// Round 9
// 227.739 us; speedup vs baseline: 1.0276x; 1.0276x over previous
//
#include <hip/hip_runtime.h>

#define ORDER 1024
#define NCOEF 1025
#define BATCH 8192

typedef float v2 __attribute__((ext_vector_type(2)));
typedef float v8sf __attribute__((ext_vector_type(8)));

// lane i reads lane i-1; lane 0 reads 0 (bound_ctrl). Single VALU instr.
__device__ __forceinline__ float wave_shr1(float v) {
    int r = __builtin_amdgcn_update_dpp(0, __float_as_int(v),
                                        0x138 /*wave_shr:1*/, 0xf, 0xf, true);
    return __int_as_float(r);
}

// 8 roots -> SGPRs on the scalar pipe (no VALU, no vmcnt).
__device__ __forceinline__ v8sf s_load8(const float* p) {
    v8sf r;
    asm volatile("s_load_dwordx8 %0, %1, 0x0" : "=s"(r) : "s"(p));
    return r;
}
__device__ __forceinline__ void s_wait8(v8sf& r) {
    asm volatile("s_waitcnt lgkmcnt(0)" : "+s"(r));
}

// Lane-local coefficient bank, stride-9 pairing on the 17-coeff cycle:
//   p[m] = (c_m, c_{m+9})  for m=0..7
// Boundary pair X = (dpp scratch = c_{-1}, c_8) ALTERNATES between two
// registers across steps: the DPP writes Xin.x, the c_8 update writes
// directly into Xout.y -> no per-step v_mov write-back.
struct Bank { v2 p[8]; };

// One step: in-place descending-m pk_fma update; reads boundary from Xin,
// writes new c_8 into Xout.y.
__device__ __forceinline__ void step(Bank& A, v2& Xin, v2& Xout, float nx) {
    v2 nxp; nxp.x = nx; nxp.y = nx;
    Xin.x = wave_shr1(A.p[7].y);                       // c_{-1}: prev lane old c_16
    Xout.y = __builtin_fmaf(nx, A.p[7].x, Xin.y);      // c_8' = c_8 + nx*c_7 (old)
#pragma unroll
    for (int m = 7; m >= 1; --m)
        A.p[m] = __builtin_elementwise_fma(nxp, A.p[m - 1], A.p[m]);
    A.p[0] = __builtin_elementwise_fma(nxp, Xin, A.p[0]);  // (c_{-1}, c_8) old
}

__global__ __launch_bounds__(256) void r2p_kernel(const float* __restrict__ x,
                                                  float* __restrict__ out) {
    const int wave = threadIdx.x >> 6;
    const int lane = threadIdx.x & 63;
    int row = (int)blockIdx.x * 4 + wave;
    row = __builtin_amdgcn_readfirstlane(row);   // wave-uniform -> scalar math

    const float* __restrict__ xr = x + (size_t)row * ORDER;
    float* __restrict__ orow = out + (size_t)row * NCOEF;

    Bank A;
#pragma unroll
    for (int m = 0; m < 8; ++m) { A.p[m].x = 0.0f; A.p[m].y = 0.0f; }
    v2 X0, X1;
    X0.x = 0.0f; X0.y = 0.0f; X1.x = 0.0f; X1.y = 0.0f;
    if (lane == 0) A.p[0].x = 1.0f;   // c_0 = 1: empty product

    // Root stream on the scalar pipe, double-buffered one 8-group ahead.
    v8sf cur = s_load8(xr);
    s_wait8(cur);
    for (int i = 0; i < ORDER; i += 8) {
        const int nextoff = (i + 8 < ORDER) ? (i + 8) : i;   // uniform, SALU
        v8sf nxt = s_load8(xr + nextoff);

        step(A, X0, X1, -cur.s0);   // X ping-pong: 8 steps (even) -> ends in X0
        step(A, X1, X0, -cur.s1);
        step(A, X0, X1, -cur.s2);
        step(A, X1, X0, -cur.s3);
        step(A, X0, X1, -cur.s4);
        step(A, X1, X0, -cur.s5);
        step(A, X0, X1, -cur.s6);
        step(A, X1, X0, -cur.s7);

        s_wait8(nxt);
        cur = nxt;    // SALU moves, overlap with VALU
    }

    // Store: k = 17*lane + j ; j=0..7 -> p[j].lo, j=8 -> X0.y, j=9..16 -> p[j-9].hi
#pragma unroll
    for (int j = 0; j < 8; ++j) {
        const int k = lane * 17 + j;
        if (k < NCOEF) orow[k] = A.p[j].x;
    }
    {
        const int k = lane * 17 + 8;
        if (k < NCOEF) orow[k] = X0.y;
    }
#pragma unroll
    for (int j = 9; j < 17; ++j) {
        const int k = lane * 17 + j;
        if (k < NCOEF) orow[k] = A.p[j - 9].y;
    }
}

extern "C" void kernel_launch(void* const* d_in, const int* in_sizes, int n_in,
                              void* d_out, int out_size, void* d_ws, size_t ws_size,
                              hipStream_t stream) {
    const float* x = (const float*)d_in[0];
    float* out = (float*)d_out;
    dim3 grid(BATCH / 4);  // 4 waves (rows) per 256-thread block
    dim3 block(256);
    hipLaunchKernelGGL(r2p_kernel, grid, block, 0, stream, x, out);
}